// Round 6
// baseline (16597.742 us; speedup 1.0000x reference)
//
#include <hip/hip_runtime.h>
#include <hip/hip_fp16.h>

#define BSZ   64
#define ILEN  1024
#define TLEN  1024
#define TTOT  2048
#define IDIM  128
#define HDIM  256
#define GDIM  1024   // 4*HDIM
#define NCLS  128
#define NUG   16     // unit-groups of 16 units
#define NP    4      // batch-tiles of 16 batches
#define GBLK  16     // blocks per sync group (= NUG)

typedef unsigned int u32;
typedef _Float16 f16x8 __attribute__((ext_vector_type(8)));
typedef float f32x4 __attribute__((ext_vector_type(4)));
typedef _Float16 h2_t __attribute__((ext_vector_type(2)));

union U4H8 { uint4 u; f16x8 h; };

__device__ __forceinline__ float fdot2(u32 a, u32 b, float acc) {
#if __has_builtin(__builtin_amdgcn_fdot2)
    union { u32 u; h2_t h; } ua, ub;
    ua.u = a; ub.u = b;
    return __builtin_amdgcn_fdot2(ua.h, ub.h, acc, false);
#else
    union { u32 u; __half2 h; } ua, ub;
    ua.u = a; ub.u = b;
    return acc + __low2float(ua.h) * __low2float(ub.h)
               + __high2float(ua.h) * __high2float(ub.h);
#endif
}

__device__ __forceinline__ u32 packf2(float x, float y) {
    __half2 h = __floats2half2_rn(x, y);
    union { __half2 h; u32 u; } c; c.h = h;
    return c.u;
}

__device__ __forceinline__ float sigm(float x) { return 1.f / (1.f + __expf(-x)); }
__device__ __forceinline__ float tanh_fast(float x) { return 1.f - 2.f / (__expf(2.f * x) + 1.f); }

// ---------------------------------------------------------------------------
// Pack weights into MFMA A-fragment order (f16).
//  Apack  (w_hh): chunk ci = (ug*4+g)*8+kt, lane l, j=0..7 holds
//       w_hh[g*256 + ug*16 + (l&15)][kt*32 + (l>>4)*8 + j]
//  Aipack (w_ih): chunk ci = (ug*4+g)*4+kt4, same row, K = kt4*32+(l>>4)*8+j
//  Wcq    (clf):  old [k4][n] uint4 layout for clf_kernel
// ---------------------------------------------------------------------------
__global__ void pack_kernel(const float* __restrict__ w_ih,
                            const float* __restrict__ w_hh,
                            const float* __restrict__ clf_w,
                            uint4* __restrict__ Apack,
                            uint4* __restrict__ Aipack,
                            uint4* __restrict__ Wcq)
{
    int i = blockIdx.x * blockDim.x + threadIdx.x;
    if (i < 32768) {                       // Apack: 512 chunks x 64 lanes
        int ci = i >> 6, l = i & 63;
        int ug = ci >> 5, g = (ci >> 3) & 3, kt = ci & 7;
        int R  = g * HDIM + ug * 16 + (l & 15);
        int K0 = kt * 32 + (l >> 4) * 8;
        const float* src = w_hh + (size_t)R * HDIM + K0;
        uint4 v;
        v.x = packf2(src[0], src[1]); v.y = packf2(src[2], src[3]);
        v.z = packf2(src[4], src[5]); v.w = packf2(src[6], src[7]);
        Apack[i] = v;
    } else if (i < 49152) {                // Aipack: 256 chunks x 64 lanes
        int r = i - 32768;
        int ci = r >> 6, l = r & 63;
        int ug = ci >> 4, g = (ci >> 2) & 3, kt4 = ci & 3;
        int R  = g * HDIM + ug * 16 + (l & 15);
        int K0 = kt4 * 32 + (l >> 4) * 8;
        const float* src = w_ih + (size_t)R * IDIM + K0;
        uint4 v;
        v.x = packf2(src[0], src[1]); v.y = packf2(src[2], src[3]);
        v.z = packf2(src[4], src[5]); v.w = packf2(src[6], src[7]);
        Aipack[r] = v;
    } else if (i < 53248) {                // Wcq (clf), unchanged layout
        int r = i - 49152;
        int n = r & (NCLS - 1);
        int k4 = r >> 7;
        const float* src = clf_w + (size_t)n * HDIM + k4 * 8;
        uint4 v;
        v.x = packf2(src[0], src[1]); v.y = packf2(src[2], src[3]);
        v.z = packf2(src[4], src[5]); v.w = packf2(src[6], src[7]);
        Wcq[r] = v;
    }
}

// ---------------------------------------------------------------------------
// Zero h-exchange buffers and flags (ws is poisoned 0xAA; must re-init every
// launch since timing replays don't re-poison and flags must start at 0).
// ---------------------------------------------------------------------------
__global__ void init_kernel(u32* __restrict__ hbuf, u32* __restrict__ flags)
{
    int i = blockIdx.x * blockDim.x + threadIdx.x;
    if (i < NP * 2 * 16 * 128) hbuf[i] = 0u;
    if (i < NP * 32) flags[i] = 0u;
}

// ---------------------------------------------------------------------------
// MFMA recurrent kernel. 64 blocks = 16 unit-groups (ug) x 4 batch-tiles (p).
// Block: 4 waves, wave g = gate g, computes z[16 units x 16 batches] via
// 8 (+4 input) chained mfma_f32_16x16x32_f16. Sync: 16-block group flag.
// ---------------------------------------------------------------------------
__global__ __launch_bounds__(256, 1) void lstm_rec(
    const float* __restrict__ inp,
    const float* __restrict__ bias_g,
    const uint4* __restrict__ Apack,
    const uint4* __restrict__ Aipack,
    __half* __restrict__ Hs,
    u32* __restrict__ hbuf,     // [NP][2][16][128] u32 (f16 pairs, [b][unit])
    u32* __restrict__ flags)    // [NP][32]
{
    __shared__ alignas(16) uint4 whA[32 * 64];        // 32 KB
    __shared__ alignas(16) uint4 wiA[16 * 64];        // 16 KB
    __shared__ float z_sh[4 * 272];                   // [g][b(16)][m pad 17]
    __shared__ __half hn_sh[256];                     // [b(16)][m(16)]

    const int ug  = blockIdx.x >> 2;
    const int p   = blockIdx.x & 3;
    const int tid = threadIdx.x;
    const int g   = tid >> 6;       // wave = gate
    const int l   = tid & 63;
    const int lq  = l >> 4;         // lane quarter (k-chunk)
    const int lm  = l & 15;         // A-row / B-col within tile

    // stage A fragments into LDS (once)
    #pragma unroll
    for (int i = 0; i < 8; ++i) whA[i * 256 + tid] = Apack[ug * 2048 + i * 256 + tid];
    #pragma unroll
    for (int i = 0; i < 4; ++i) wiA[i * 256 + tid] = Aipack[ug * 1024 + i * 256 + tid];

    // bias for this lane's 4 accumulator rows (D row = lq*4 + r)
    const float br0 = bias_g[g * HDIM + ug * 16 + lq * 4 + 0];
    const float br1 = bias_g[g * HDIM + ug * 16 + lq * 4 + 1];
    const float br2 = bias_g[g * HDIM + ug * 16 + lq * 4 + 2];
    const float br3 = bias_g[g * HDIM + ug * 16 + lq * 4 + 3];

    // epilogue identity: thread = (batch eb, unit em); c-state in register
    const int eb = tid >> 4;
    const int em = tid & 15;
    float c = 0.f;

    u32* flag = flags + p * 32;

    for (int t = 0; t < TTOT; ++t) {
        // ---- x B-fragments: issue global loads BEFORE the poll (independent)
        uint4 bx[4];
        if (t < ILEN) {
            const float* xr = inp + ((size_t)(p * 16 + lm) * ILEN + t) * IDIM + lq * 8;
            #pragma unroll
            for (int kt4 = 0; kt4 < 4; ++kt4) {
                float4 a = *(const float4*)(xr + kt4 * 32);
                float4 b = *(const float4*)(xr + kt4 * 32 + 4);
                bx[kt4].x = packf2(a.x, a.y);
                bx[kt4].y = packf2(a.z, a.w);
                bx[kt4].z = packf2(b.x, b.y);
                bx[kt4].w = packf2(b.z, b.w);
            }
        }

        // ---- wait for group to finish step t-1 (all waves poll, same addr)
        if (t > 0) {
            const u32 target = (u32)(GBLK * t);
            while (__hip_atomic_load(flag, __ATOMIC_ACQUIRE, __HIP_MEMORY_SCOPE_AGENT) < target)
                __builtin_amdgcn_s_sleep(1);
        }

        // ---- h B-fragments from exchange buffer (L2-resident)
        uint4 hb[8];
        {
            u32* hr = hbuf + ((p * 2 + (t & 1)) * 16 + lm) * 128 + lq * 4;
            #pragma unroll
            for (int kt = 0; kt < 8; ++kt) {
                hb[kt].x = __hip_atomic_load(hr + kt * 16 + 0, __ATOMIC_RELAXED, __HIP_MEMORY_SCOPE_AGENT);
                hb[kt].y = __hip_atomic_load(hr + kt * 16 + 1, __ATOMIC_RELAXED, __HIP_MEMORY_SCOPE_AGENT);
                hb[kt].z = __hip_atomic_load(hr + kt * 16 + 2, __ATOMIC_RELAXED, __HIP_MEMORY_SCOPE_AGENT);
                hb[kt].w = __hip_atomic_load(hr + kt * 16 + 3, __ATOMIC_RELAXED, __HIP_MEMORY_SCOPE_AGENT);
            }
        }

        // ---- MFMA chain: z = W_hh*h (+ W_ih*x) + bias
        f32x4 acc = {br0, br1, br2, br3};
        #pragma unroll
        for (int kt = 0; kt < 8; ++kt) {
            U4H8 a, b;
            a.u = whA[(g * 8 + kt) * 64 + l];
            b.u = hb[kt];
            acc = __builtin_amdgcn_mfma_f32_16x16x32_f16(a.h, b.h, acc, 0, 0, 0);
        }
        if (t < ILEN) {
            #pragma unroll
            for (int kt4 = 0; kt4 < 4; ++kt4) {
                U4H8 a, b;
                a.u = wiA[(g * 4 + kt4) * 64 + l];
                b.u = bx[kt4];
                acc = __builtin_amdgcn_mfma_f32_16x16x32_f16(a.h, b.h, acc, 0, 0, 0);
            }
        }

        // ---- z to LDS: D element (row = lq*4+r, col = lm) -> z_sh[g][col][row]
        #pragma unroll
        for (int r = 0; r < 4; ++r)
            z_sh[g * 272 + lm * 17 + lq * 4 + r] = acc[r];
        __syncthreads();

        // ---- epilogue: gates, c/h update
        {
            float zi = z_sh[0 * 272 + eb * 17 + em];
            float zf = z_sh[1 * 272 + eb * 17 + em];
            float zg = z_sh[2 * 272 + eb * 17 + em];
            float zo = z_sh[3 * 272 + eb * 17 + em];
            float ig = sigm(zi);
            float fg = sigm(zf);
            float gg = tanh_fast(zg);
            float og = sigm(zo);
            c = fg * c + ig * gg;
            float hn = og * tanh_fast(c);
            __half hh = __float2half(hn);
            hn_sh[eb * 16 + em] = hh;
            if (t >= ILEN)
                Hs[((size_t)(p * 16 + eb) * TLEN + (t - ILEN)) * HDIM + ug * 16 + em] = hh;
        }
        __syncthreads();

        // ---- publish h slice (u32 pairs) to exchange buffer
        if (tid < 128) {
            u32 v = ((const u32*)hn_sh)[tid];
            int b2 = tid >> 3, mw = tid & 7;
            __hip_atomic_store(hbuf + ((p * 2 + ((t + 1) & 1)) * 16 + b2) * 128 + ug * 8 + mw,
                               v, __ATOMIC_RELAXED, __HIP_MEMORY_SCOPE_AGENT);
        }
        __syncthreads();   // drains stores (compiler emits vmcnt(0) before barrier)

        if (tid == 0)
            __hip_atomic_fetch_add(flag, 1u, __ATOMIC_RELEASE, __HIP_MEMORY_SCOPE_AGENT);
    }
}

// ---------------------------------------------------------------------------
// Classifier: out[b][t][n] = clf_b[n] + clf_w[n]·h[b][t]. (unchanged)
// ---------------------------------------------------------------------------
#define CTT 16
__global__ __launch_bounds__(256) void clf_kernel(
    const uint4* __restrict__ Wcq,
    const __half* __restrict__ Hs,
    const float* __restrict__ clf_b,
    float* __restrict__ out)
{
    __shared__ alignas(16) u32 h_sh[CTT * (HDIM / 2)];   // 8 KB
    const int tid = threadIdx.x;
    const int b  = blockIdx.x >> 6;
    const int t0 = (blockIdx.x & 63) * CTT;

    const uint4* hsrc = (const uint4*)(Hs + ((size_t)b * TLEN + t0) * HDIM);
    uint4* hdst = (uint4*)h_sh;
    hdst[tid]       = hsrc[tid];
    hdst[tid + 256] = hsrc[tid + 256];
    __syncthreads();

    const int n  = tid & (NCLS - 1);
    const int tl = tid >> 7;
    const float bias = clf_b[n];
    float acc[8];
    #pragma unroll
    for (int q = 0; q < 8; ++q) acc[q] = bias;

    #pragma unroll 4
    for (int k4 = 0; k4 < HDIM / 8; ++k4) {
        uint4 w = Wcq[k4 * NCLS + n];
        #pragma unroll
        for (int q = 0; q < 8; ++q) {
            const uint4* hp = (const uint4*)(h_sh + (tl + 2 * q) * (HDIM / 2));
            uint4 h = hp[k4];
            acc[q] = fdot2(w.x, h.x, acc[q]);
            acc[q] = fdot2(w.y, h.y, acc[q]);
            acc[q] = fdot2(w.z, h.z, acc[q]);
            acc[q] = fdot2(w.w, h.w, acc[q]);
        }
    }
    #pragma unroll
    for (int q = 0; q < 8; ++q) {
        out[((size_t)b * TLEN + t0 + tl + 2 * q) * NCLS + n] = acc[q];
    }
}

// ---------------------------------------------------------------------------
extern "C" void kernel_launch(void* const* d_in, const int* in_sizes, int n_in,
                              void* d_out, int out_size, void* d_ws, size_t ws_size,
                              hipStream_t stream)
{
    const float* inp   = (const float*)d_in[0];
    // d_in[1] = tlen (1024, hardcoded)
    const float* w_ih  = (const float*)d_in[2];
    const float* w_hh  = (const float*)d_in[3];
    const float* bias  = (const float*)d_in[4];
    const float* clf_w = (const float*)d_in[5];
    const float* clf_b = (const float*)d_in[6];
    float* out = (float*)d_out;

    char* ws = (char*)d_ws;
    uint4*  Apack  = (uint4*)(ws);                    // 512 KB
    uint4*  Aipack = (uint4*)(ws + 524288);           // 256 KB
    uint4*  Wcq    = (uint4*)(ws + 786432);           // 64 KB
    __half* Hs     = (__half*)(ws + 851968);          // 33.55 MB
    u32*    hbuf   = (u32*)(ws + 34406400);           // 64 KB
    u32*    flags  = (u32*)(ws + 34471936);           // 512 B

    init_kernel<<<64, 256, 0, stream>>>(hbuf, flags);
    pack_kernel<<<208, 256, 0, stream>>>(w_ih, w_hh, clf_w, Apack, Aipack, Wcq);

    void* args[] = {(void*)&inp, (void*)&bias, (void*)&Apack, (void*)&Aipack,
                    (void*)&Hs, (void*)&hbuf, (void*)&flags};
    hipLaunchCooperativeKernel((const void*)lstm_rec,
                               dim3(NUG * NP), dim3(256), args, 0, stream);

    clf_kernel<<<BSZ * (TLEN / CTT), 256, 0, stream>>>(Wcq, Hs, clf_b, out);
}

// Round 7
// 7688.729 us; speedup vs baseline: 2.1587x; 2.1587x over previous
//
#include <hip/hip_runtime.h>
#include <hip/hip_fp16.h>

#define BSZ   64
#define ILEN  1024
#define TLEN  1024
#define TTOT  2048
#define IDIM  128
#define HDIM  256
#define GDIM  1024   // 4*HDIM
#define NCLS  128
#define NGRP  8      // groups (one per XCD), 8 batches each
#define NMEM  4      // member blocks per group, 64 units each
#define BPG   8      // batches per group

typedef unsigned int u32;
typedef _Float16 f16x8 __attribute__((ext_vector_type(8)));
typedef float f32x4 __attribute__((ext_vector_type(4)));
typedef _Float16 h2_t __attribute__((ext_vector_type(2)));

union U4H8 { uint4 u; f16x8 h; };

__device__ __forceinline__ float fdot2(u32 a, u32 b, float acc) {
#if __has_builtin(__builtin_amdgcn_fdot2)
    union { u32 u; h2_t h; } ua, ub;
    ua.u = a; ub.u = b;
    return __builtin_amdgcn_fdot2(ua.h, ub.h, acc, false);
#else
    union { u32 u; __half2 h; } ua, ub;
    ua.u = a; ub.u = b;
    return acc + __low2float(ua.h) * __low2float(ub.h)
               + __high2float(ua.h) * __high2float(ub.h);
#endif
}

__device__ __forceinline__ u32 packf2(float x, float y) {
    __half2 h = __floats2half2_rn(x, y);
    union { __half2 h; u32 u; } c; c.h = h;
    return c.u;
}

__device__ __forceinline__ float sigm(float x) { return 1.f / (1.f + __expf(-x)); }
__device__ __forceinline__ float tanh_fast(float x) { return 1.f - 2.f / (__expf(2.f * x) + 1.f); }

// ---------------------------------------------------------------------------
// Pack weights into MFMA A-fragment order (f16).  (unchanged from R6 —
// fragment layout verified correct by R6's passing absmax.)
//  Apack  (w_hh): chunk ci = ug*32 + g*8 + kt, lane l, j=0..7 holds
//       w_hh[g*256 + ug*16 + (l&15)][kt*32 + (l>>4)*8 + j]
//  Aipack (w_ih): chunk ci = ug*16 + g*4 + kt4, same row, K = kt4*32+(l>>4)*8+j
//  Wcq    (clf):  [k4][n] uint4 layout for clf_kernel
// ---------------------------------------------------------------------------
__global__ void pack_kernel(const float* __restrict__ w_ih,
                            const float* __restrict__ w_hh,
                            const float* __restrict__ clf_w,
                            uint4* __restrict__ Apack,
                            uint4* __restrict__ Aipack,
                            uint4* __restrict__ Wcq)
{
    int i = blockIdx.x * blockDim.x + threadIdx.x;
    if (i < 32768) {                       // Apack: 512 chunks x 64 lanes
        int ci = i >> 6, l = i & 63;
        int ug = ci >> 5, g = (ci >> 3) & 3, kt = ci & 7;
        int R  = g * HDIM + ug * 16 + (l & 15);
        int K0 = kt * 32 + (l >> 4) * 8;
        const float* src = w_hh + (size_t)R * HDIM + K0;
        uint4 v;
        v.x = packf2(src[0], src[1]); v.y = packf2(src[2], src[3]);
        v.z = packf2(src[4], src[5]); v.w = packf2(src[6], src[7]);
        Apack[i] = v;
    } else if (i < 49152) {                // Aipack: 256 chunks x 64 lanes
        int r = i - 32768;
        int ci = r >> 6, l = r & 63;
        int ug = ci >> 4, g = (ci >> 2) & 3, kt4 = ci & 3;
        int R  = g * HDIM + ug * 16 + (l & 15);
        int K0 = kt4 * 32 + (l >> 4) * 8;
        const float* src = w_ih + (size_t)R * IDIM + K0;
        uint4 v;
        v.x = packf2(src[0], src[1]); v.y = packf2(src[2], src[3]);
        v.z = packf2(src[4], src[5]); v.w = packf2(src[6], src[7]);
        Aipack[r] = v;
    } else if (i < 53248) {                // Wcq (clf)
        int r = i - 49152;
        int n = r & (NCLS - 1);
        int k4 = r >> 7;
        const float* src = clf_w + (size_t)n * HDIM + k4 * 8;
        uint4 v;
        v.x = packf2(src[0], src[1]); v.y = packf2(src[2], src[3]);
        v.z = packf2(src[4], src[5]); v.w = packf2(src[6], src[7]);
        Wcq[r] = v;
    }
}

// ---------------------------------------------------------------------------
// Zero h-exchange buffers and flags (ws is poisoned 0xAA once; flags must
// start at 0 and h at exact 0 on every launch).
// ---------------------------------------------------------------------------
__global__ void init_kernel(u32* __restrict__ hbuf, u32* __restrict__ flags)
{
    int i = blockIdx.x * blockDim.x + threadIdx.x;
    if (i < NGRP * 2 * BPG * 128) hbuf[i] = 0u;
    if (i < NGRP * 16) flags[i] = 0u;
}

// ---------------------------------------------------------------------------
// MFMA recurrent kernel. 32 blocks = 8 groups (blk&7, one XCD each under
// round-robin) x 4 members (blk>>3). Group owns 8 batches; member owns
// 64 units x 4 gates. Per-block per-member flag slot (no RMW contention).
// w_hh A-fragments in LDS (128 KB); w_ih A-frags + x loaded pre-poll.
// ---------------------------------------------------------------------------
__global__ __launch_bounds__(256, 1) void lstm_rec(
    const float* __restrict__ inp,
    const float* __restrict__ bias_g,
    const uint4* __restrict__ Apack,
    const uint4* __restrict__ Aipack,
    __half* __restrict__ Hs,
    u32* __restrict__ hbuf,     // [NGRP][2][BPG][128] u32 (f16 pairs [b][unit/2])
    u32* __restrict__ flags)    // [NGRP][16] (slot = member, one line/group)
{
    __shared__ alignas(16) uint4 whA[128 * 64];     // 128 KB
    __shared__ alignas(16) u32   hB[16 * 132];      // 8.25 KB (rows 8-15 unused)
    __shared__ float z_sh[4 * BPG * 72];            // 9 KB [gate][b][unit72]

    const int blk    = blockIdx.x;
    const int g      = blk & 7;       // group / XCD
    const int member = blk >> 3;      // 0..3: units [member*64, +64)
    const int tid = threadIdx.x;
    const int w   = tid >> 6;         // wave = gate
    const int l   = tid & 63;
    const int lq  = l >> 4;           // k-quarter
    const int lm  = l & 15;           // A-row / B-col (batch; 8 valid)

    // ---- stage w_hh A-fragments into LDS (once): dest chunk d = w*32+rt*8+kt
    #pragma unroll
    for (int s = 0; s < 32; ++s) {
        int gi = s * 256 + tid;
        int d  = gi >> 6, l2 = gi & 63;
        int gate = d >> 5, rt = (d >> 3) & 3, kt = d & 7;
        whA[gi] = Apack[(((member * 4 + rt) * 32) + gate * 8 + kt) * 64 + l2];
    }

    // ---- bias for this lane's accumulator rows
    float bias_r[4][4];
    #pragma unroll
    for (int rt = 0; rt < 4; ++rt)
        #pragma unroll
        for (int r = 0; r < 4; ++r)
            bias_r[rt][r] = bias_g[w * HDIM + member * 64 + rt * 16 + lq * 4 + r];

    // ---- epilogue identity: thread = (batch b_e, unit pair u2); c in regs
    const int b_e = tid >> 5;         // 0..7
    const int u2  = tid & 31;         // u32 col: units 2*u2, 2*u2+1
    float c0 = 0.f, c1 = 0.f;

    const uint4* hB4 = (const uint4*)hB;
    u32* fl = flags + g * 16;

    for (int t = 0; t < TTOT; ++t) {
        // ---- phase 0: issue x + w_ih loads (independent of h; hide under poll)
        uint4 bx[4];
        uint4 wiAr[4][4];
        if (t < ILEN) {
            if (lm < 8) {
                const float* xr = inp + ((size_t)(g * 8 + lm) * ILEN + t) * IDIM + lq * 8;
                #pragma unroll
                for (int kt4 = 0; kt4 < 4; ++kt4) {
                    float4 a = *(const float4*)(xr + kt4 * 32);
                    float4 b = *(const float4*)(xr + kt4 * 32 + 4);
                    bx[kt4].x = packf2(a.x, a.y);
                    bx[kt4].y = packf2(a.z, a.w);
                    bx[kt4].z = packf2(b.x, b.y);
                    bx[kt4].w = packf2(b.z, b.w);
                }
            }
            #pragma unroll
            for (int rt = 0; rt < 4; ++rt)
                #pragma unroll
                for (int kt4 = 0; kt4 < 4; ++kt4)
                    wiAr[rt][kt4] = Aipack[(((member * 4 + rt) * 16) + w * 4 + kt4) * 64 + l];
        }

        // ---- phase 1: wait for all 4 members to finish step t-1
        if (t > 0) {
            while (true) {
                u32 v = __hip_atomic_load(fl + (l & 3), __ATOMIC_ACQUIRE,
                                          __HIP_MEMORY_SCOPE_AGENT);
                if (__all(v >= (u32)t)) break;
                __builtin_amdgcn_s_sleep(1);
            }
        }

        // ---- phase 2: stage h (4 KB) into LDS
        {
            const int r  = tid >> 5;          // batch row 0..7
            const int c0i = (tid & 31) * 4;   // u32 cols
            const u32* hr = hbuf + (((size_t)g * 2 + (t & 1)) * BPG + r) * 128 + c0i;
            u32 v0 = __hip_atomic_load(hr + 0, __ATOMIC_RELAXED, __HIP_MEMORY_SCOPE_AGENT);
            u32 v1 = __hip_atomic_load(hr + 1, __ATOMIC_RELAXED, __HIP_MEMORY_SCOPE_AGENT);
            u32 v2 = __hip_atomic_load(hr + 2, __ATOMIC_RELAXED, __HIP_MEMORY_SCOPE_AGENT);
            u32 v3 = __hip_atomic_load(hr + 3, __ATOMIC_RELAXED, __HIP_MEMORY_SCOPE_AGENT);
            hB[r * 132 + c0i + 0] = v0;
            hB[r * 132 + c0i + 1] = v1;
            hB[r * 132 + c0i + 2] = v2;
            hB[r * 132 + c0i + 3] = v3;
        }

        // ---- x-MFMAs while h staging settles (acc init with bias)
        f32x4 acc[4];
        #pragma unroll
        for (int rt = 0; rt < 4; ++rt)
            acc[rt] = (f32x4){bias_r[rt][0], bias_r[rt][1], bias_r[rt][2], bias_r[rt][3]};
        if (t < ILEN) {
            #pragma unroll
            for (int kt4 = 0; kt4 < 4; ++kt4) {
                U4H8 b; b.u = bx[kt4];
                #pragma unroll
                for (int rt = 0; rt < 4; ++rt) {
                    U4H8 a; a.u = wiAr[rt][kt4];
                    acc[rt] = __builtin_amdgcn_mfma_f32_16x16x32_f16(a.h, b.h, acc[rt], 0, 0, 0);
                }
            }
        }
        __syncthreads();   // hB ready

        // ---- phase 3: h-MFMAs
        #pragma unroll
        for (int kt = 0; kt < 8; ++kt) {
            U4H8 b; b.u = hB4[lm * 33 + kt * 4 + lq];
            #pragma unroll
            for (int rt = 0; rt < 4; ++rt) {
                U4H8 a; a.u = whA[((w * 4 + rt) * 8 + kt) * 64 + l];
                acc[rt] = __builtin_amdgcn_mfma_f32_16x16x32_f16(a.h, b.h, acc[rt], 0, 0, 0);
            }
        }

        // ---- phase 4: z -> LDS (cols 0..7 only)
        if (lm < 8) {
            #pragma unroll
            for (int rt = 0; rt < 4; ++rt)
                #pragma unroll
                for (int r = 0; r < 4; ++r)
                    z_sh[(w * BPG + lm) * 72 + rt * 16 + lq * 4 + r] = acc[rt][r];
        }
        __syncthreads();   // z ready

        // ---- phase 5: epilogue (thread = batch b_e, units 2u2/2u2+1)
        {
            float zi0 = z_sh[(0 * BPG + b_e) * 72 + 2 * u2];
            float zi1 = z_sh[(0 * BPG + b_e) * 72 + 2 * u2 + 1];
            float zf0 = z_sh[(1 * BPG + b_e) * 72 + 2 * u2];
            float zf1 = z_sh[(1 * BPG + b_e) * 72 + 2 * u2 + 1];
            float zg0 = z_sh[(2 * BPG + b_e) * 72 + 2 * u2];
            float zg1 = z_sh[(2 * BPG + b_e) * 72 + 2 * u2 + 1];
            float zo0 = z_sh[(3 * BPG + b_e) * 72 + 2 * u2];
            float zo1 = z_sh[(3 * BPG + b_e) * 72 + 2 * u2 + 1];
            c0 = sigm(zf0) * c0 + sigm(zi0) * tanh_fast(zg0);
            c1 = sigm(zf1) * c1 + sigm(zi1) * tanh_fast(zg1);
            float h0 = sigm(zo0) * tanh_fast(c0);
            float h1 = sigm(zo1) * tanh_fast(c1);
            u32 hp = packf2(h0, h1);
            // publish to exchange buffer, parity (t+1)&1
            __hip_atomic_store(hbuf + (((size_t)g * 2 + ((t + 1) & 1)) * BPG + b_e) * 128
                                    + member * 32 + u2,
                               hp, __ATOMIC_RELAXED, __HIP_MEMORY_SCOPE_AGENT);
            if (t >= ILEN) {
                u32* hsrow = (u32*)(Hs + ((size_t)(g * 8 + b_e) * TLEN + (t - ILEN)) * HDIM
                                       + member * 64);
                hsrow[u2] = hp;
            }
        }
        __syncthreads();   // publish stores drained (vmcnt0 before barrier)

        if (tid == 0)
            __hip_atomic_store(&fl[member], (u32)(t + 1), __ATOMIC_RELEASE,
                               __HIP_MEMORY_SCOPE_AGENT);
    }
}

// ---------------------------------------------------------------------------
// Classifier: out[b][t][n] = clf_b[n] + clf_w[n]·h[b][t]. (unchanged)
// ---------------------------------------------------------------------------
#define CTT 16
__global__ __launch_bounds__(256) void clf_kernel(
    const uint4* __restrict__ Wcq,
    const __half* __restrict__ Hs,
    const float* __restrict__ clf_b,
    float* __restrict__ out)
{
    __shared__ alignas(16) u32 h_sh[CTT * (HDIM / 2)];   // 8 KB
    const int tid = threadIdx.x;
    const int b  = blockIdx.x >> 6;
    const int t0 = (blockIdx.x & 63) * CTT;

    const uint4* hsrc = (const uint4*)(Hs + ((size_t)b * TLEN + t0) * HDIM);
    uint4* hdst = (uint4*)h_sh;
    hdst[tid]       = hsrc[tid];
    hdst[tid + 256] = hsrc[tid + 256];
    __syncthreads();

    const int n  = tid & (NCLS - 1);
    const int tl = tid >> 7;
    const float bias = clf_b[n];
    float acc[8];
    #pragma unroll
    for (int q = 0; q < 8; ++q) acc[q] = bias;

    #pragma unroll 4
    for (int k4 = 0; k4 < HDIM / 8; ++k4) {
        uint4 w = Wcq[k4 * NCLS + n];
        #pragma unroll
        for (int q = 0; q < 8; ++q) {
            const uint4* hp = (const uint4*)(h_sh + (tl + 2 * q) * (HDIM / 2));
            uint4 h = hp[k4];
            acc[q] = fdot2(w.x, h.x, acc[q]);
            acc[q] = fdot2(w.y, h.y, acc[q]);
            acc[q] = fdot2(w.z, h.z, acc[q]);
            acc[q] = fdot2(w.w, h.w, acc[q]);
        }
    }
    #pragma unroll
    for (int q = 0; q < 8; ++q) {
        out[((size_t)b * TLEN + t0 + tl + 2 * q) * NCLS + n] = acc[q];
    }
}

// ---------------------------------------------------------------------------
extern "C" void kernel_launch(void* const* d_in, const int* in_sizes, int n_in,
                              void* d_out, int out_size, void* d_ws, size_t ws_size,
                              hipStream_t stream)
{
    const float* inp   = (const float*)d_in[0];
    // d_in[1] = tlen (1024, hardcoded)
    const float* w_ih  = (const float*)d_in[2];
    const float* w_hh  = (const float*)d_in[3];
    const float* bias  = (const float*)d_in[4];
    const float* clf_w = (const float*)d_in[5];
    const float* clf_b = (const float*)d_in[6];
    float* out = (float*)d_out;

    char* ws = (char*)d_ws;
    uint4*  Apack  = (uint4*)(ws);                    // 512 KB
    uint4*  Aipack = (uint4*)(ws + 524288);           // 256 KB
    uint4*  Wcq    = (uint4*)(ws + 786432);           // 64 KB
    __half* Hs     = (__half*)(ws + 851968);          // 33.55 MB
    u32*    hbuf   = (u32*)(ws + 34406400);           // 64 KB
    u32*    flags  = (u32*)(ws + 34471936);           // 512 B

    init_kernel<<<64, 256, 0, stream>>>(hbuf, flags);
    pack_kernel<<<208, 256, 0, stream>>>(w_ih, w_hh, clf_w, Apack, Aipack, Wcq);

    void* args[] = {(void*)&inp, (void*)&bias, (void*)&Apack, (void*)&Aipack,
                    (void*)&Hs, (void*)&hbuf, (void*)&flags};
    hipLaunchCooperativeKernel((const void*)lstm_rec,
                               dim3(NGRP * NMEM), dim3(256), args, 0, stream);

    clf_kernel<<<BSZ * (TLEN / CTT), 256, 0, stream>>>(Wcq, Hs, clf_b, out);
}